// Round 9
// baseline (289.055 us; speedup 1.0000x reference)
//
#include <hip/hip_runtime.h>
#include <hip/hip_bf16.h>
#include <cmath>

typedef __bf16 bf16_t;
typedef __attribute__((ext_vector_type(8))) __bf16 bf16x8;
typedef __attribute__((ext_vector_type(4))) float f32x4;
typedef __attribute__((ext_vector_type(4))) short s16x4;

#define S_LEN 2048
#define DMODEL 2048
#define KVDIM 512
#define NHEADS 32
#define NKV 8
#define HDIM 64

__device__ inline f32x4 zero4() { f32x4 z; z[0]=0.f; z[1]=0.f; z[2]=0.f; z[3]=0.f; return z; }

// Inputs are fp32 (established R2-R6: bf16 misread would NaN; we pass at 1.46e-3).
// One dispatch converts all 5 tensors to bf16. 2048 elems/block:
// x 2048 | Wq 2048 | Wk 512 | Wv 512 | Wo 2048 blocks (7168 total).
__global__ void convert_all(const float* __restrict__ s0, bf16_t* __restrict__ d0,
                            const float* __restrict__ s1, bf16_t* __restrict__ d1,
                            const float* __restrict__ s2, bf16_t* __restrict__ d2,
                            const float* __restrict__ s3, bf16_t* __restrict__ d3,
                            const float* __restrict__ s4, bf16_t* __restrict__ d4) {
  int b = blockIdx.x;
  const float* src; bf16_t* dst; int boff;
  if      (b < 2048) { src = s0; dst = d0; boff = b; }
  else if (b < 4096) { src = s1; dst = d1; boff = b - 2048; }
  else if (b < 4608) { src = s2; dst = d2; boff = b - 4096; }
  else if (b < 5120) { src = s3; dst = d3; boff = b - 4608; }
  else               { src = s4; dst = d4; boff = b - 5120; }
  int idx = (boff * 256 + threadIdx.x) * 8;
  bf16x8 v;
#pragma unroll
  for (int j = 0; j < 8; j++) v[j] = (bf16_t)src[idx + j];
  *(bf16x8*)(dst + idx) = v;
}

// GEMM core: C = A(MxK) * Bt(NxK)^T, bf16 in, fp32 accum. Tile 128 x BN, BK=64,
// 4 waves 2x2.
// R14/R15: 3-stage pipeline with COUNTED vmcnt (T4). R13's dbuf+__syncthreads
// was null because syncthreads drains vmcnt(0) -- it waits for the just-issued
// prefetch too, re-exposing ~500cy of load latency every K-step (m218:
// counted-vs-drain0 is the entire dbuf gain). Now: 3 LDS buffers (72KB,
// 2 blocks/CU); per wave each stage = exactly 6 global_load_lds (4A+2B), so
// s_waitcnt vmcnt(6) waits only the OLDEST 6 (tile issued 2 compute phases
// ~800cy ago -> landed), leaving the newest 6 in flight across the barrier.
// ONE raw s_barrier per K-step serves WAR + readiness (per-wave vmcnt precedes
// it). sched_barrier(0) after waitcnt per guide rule #18.
// (R15 = R14 resubmit: R14 bench died to container-infra failure, no kernel
// evidence; barrier-matching/vmcnt/WAR/LDS audit found no defect.)
template <int BN, bool F32OUT>
__device__ __forceinline__ void gemm_core(const bf16_t* __restrict__ A,
                                          const bf16_t* __restrict__ Bt,
                                          void* __restrict__ Cout,
                                          int N, int K, int bm, int bn) {
  constexpr int NT_W = BN / 32;    // 16-col acc tiles per wave
  __shared__ __attribute__((aligned(16))) bf16_t As[3][128 * 64];
  __shared__ __attribute__((aligned(16))) bf16_t Bs[3][BN * 64];
  const int tid  = threadIdx.x;
  const int wave = tid >> 6, lane = tid & 63;
  const int wm = wave >> 1, wn = wave & 1;
  const int quad = lane >> 4, lr = lane & 15;
  const int srow = lane >> 3, scol = lane & 7;

  f32x4 acc[4][NT_W];
#pragma unroll
  for (int i = 0; i < 4; i++)
#pragma unroll
    for (int j = 0; j < NT_W; j++) acc[i][j] = zero4();

#define G_STAGE(BUF, K0)                                                                 \
  {                                                                                      \
    _Pragma("unroll")                                                                    \
    for (int i = 0; i < 4; i++) {                                                        \
      const bf16_t* gA = A + (size_t)(bm + i * 32 + wave * 8 + srow) * K + (K0) + scol * 8; \
      bf16_t* lA = As[BUF] + (i * 32 + wave * 8) * 64;                                   \
      __builtin_amdgcn_global_load_lds((const __attribute__((address_space(1))) void*)gA,\
                                       (__attribute__((address_space(3))) void*)lA, 16, 0, 0); \
    }                                                                                    \
    _Pragma("unroll")                                                                    \
    for (int i = 0; i < BN / 32; i++) {                                                  \
      const bf16_t* gB = Bt + (size_t)(bn + i * 32 + wave * 8 + srow) * K + (K0) + scol * 8; \
      bf16_t* lB = Bs[BUF] + (i * 32 + wave * 8) * 64;                                   \
      __builtin_amdgcn_global_load_lds((const __attribute__((address_space(1))) void*)gB,\
                                       (__attribute__((address_space(3))) void*)lB, 16, 0, 0); \
    }                                                                                    \
  }

  const int nt = K / 64;
  // Prologue: stage tiles 0 and 1; wait only tile 0 (vmcnt(6) leaves tile 1 in flight).
  G_STAGE(0, 0);
  G_STAGE(1, 64);
  asm volatile("s_waitcnt vmcnt(6)" ::: "memory");
  __builtin_amdgcn_sched_barrier(0);
  __builtin_amdgcn_s_barrier();

  for (int t = 0; t < nt; ++t) {
    if (t + 2 < nt) G_STAGE((t + 2) % 3, (t + 2) * 64);
    const bf16_t* Ac = As[t % 3];
    const bf16_t* Bc = Bs[t % 3];
#pragma unroll
    for (int ks = 0; ks < 2; ks++) {
      bf16x8 a[4], b[NT_W];
#pragma unroll
      for (int mt = 0; mt < 4; mt++)
        a[mt] = *(const bf16x8*)&Ac[(wm * 64 + mt * 16 + lr) * 64 + ks * 32 + quad * 8];
#pragma unroll
      for (int nt2 = 0; nt2 < NT_W; nt2++)
        b[nt2] = *(const bf16x8*)&Bc[(wn * (BN / 2) + nt2 * 16 + lr) * 64 + ks * 32 + quad * 8];
#pragma unroll
      for (int mt = 0; mt < 4; mt++)
#pragma unroll
        for (int nt2 = 0; nt2 < NT_W; nt2++)
          acc[mt][nt2] = __builtin_amdgcn_mfma_f32_16x16x32_bf16(a[mt], b[nt2], acc[mt][nt2], 0, 0, 0);
    }
    if (t + 1 < nt) {
      // Wait for tile t+1's 6 loads (oldest outstanding); keep tile t+2's 6 in flight.
      if (t + 2 < nt) asm volatile("s_waitcnt vmcnt(6)" ::: "memory");
      else            asm volatile("s_waitcnt vmcnt(0)" ::: "memory");
      __builtin_amdgcn_sched_barrier(0);
      // Single barrier: all waves (a) finished reading buf t%3 (WAR vs the
      // stage into t%3 at iter t+1) and (b) passed their own vmcnt -> t+1 ready.
      __builtin_amdgcn_s_barrier();
    }
  }
#undef G_STAGE

#pragma unroll
  for (int mt = 0; mt < 4; mt++)
#pragma unroll
    for (int nt2 = 0; nt2 < NT_W; nt2++)
#pragma unroll
      for (int r = 0; r < 4; r++) {
        int row = bm + wm * 64 + mt * 16 + quad * 4 + r;
        int col = bn + wn * (BN / 2) + nt2 * 16 + lr;
        if (F32OUT) ((float*)Cout)[(size_t)row * N + col] = acc[mt][nt2][r];
        else ((bf16_t*)Cout)[(size_t)row * N + col] = (bf16_t)acc[mt][nt2][r];
      }
}

// XCD chunk swizzle (T1, kept from R13 -- neutral but harmless): XCD c gets an
// 8bm x 8bn super-tile so its 4MB L2 holds a 6MB working set instead of 16MB.
__device__ __forceinline__ void xcd_tile(int b, int& bm, int& bn) {
  int c = b & 7, t = b >> 3;
  bm = (((c >> 2) << 3) + (t >> 3)) * 128;   // [0,16) * 128
  bn = (((c & 3) << 3) + (t & 7)) * 64;      // [0,32) * 64
}

// All three projections, one dispatch, 768 blocks of 128x64 tiles:
// 0..511: q = x Wq^T (XCD-swizzled); 512..639: k = x Wk^T; 640..767: vT = Wv x^T.
__global__ __launch_bounds__(256) void gemm_proj(const bf16_t* __restrict__ xb,
                                                 const bf16_t* __restrict__ Wqb,
                                                 const bf16_t* __restrict__ Wkb,
                                                 const bf16_t* __restrict__ Wvb,
                                                 bf16_t* __restrict__ qb,
                                                 bf16_t* __restrict__ kb,
                                                 bf16_t* __restrict__ vb) {
  int b = blockIdx.x;
  if (b < 512) {
    int bm, bn;
    xcd_tile(b, bm, bn);
    gemm_core<64, false>(xb, Wqb, qb, 2048, 2048, bm, bn);
  } else if (b < 640) {
    int r = b - 512;
    gemm_core<64, false>(xb, Wkb, kb, 512, 2048, (r >> 3) * 128, (r & 7) * 64);
  } else {
    int r = b - 640;
    gemm_core<64, false>(Wvb, xb, vb, 2048, 2048, (r >> 5) * 128, (r & 31) * 64);
  }
}

// Final projection: out = attn_out Wo^T, fp32 stores. 512 blocks, XCD-swizzled.
__global__ __launch_bounds__(256) void gemm_out(const bf16_t* __restrict__ A,
                                                const bf16_t* __restrict__ Bt,
                                                float* __restrict__ C) {
  int bm, bn;
  xcd_tile(blockIdx.x, bm, bn);
  gemm_core<64, true>(A, Bt, C, 2048, 2048, bm, bn);
}

// RoPE on k only (q is roped in-register inside attn).
__global__ void rope_k(bf16_t* __restrict__ kb) {
  int idx = blockIdx.x * 256 + threadIdx.x;
  int s = idx >> 8;                 // 256 pairs per row (KVDIM/2)
  int rem = idx & 255;
  int head = rem >> 5;
  int i = rem & 31;
  float freq = __expf(-0.2878231366f * (float)i);   // 10000^(-i/32)
  float ang = (float)s * freq;
  float sn, cs;
  sincosf(ang, &sn, &cs);
  size_t base = (size_t)s * KVDIM + head * 64 + i;
  float x0 = (float)kb[base];
  float x1 = (float)kb[base + 32];
  kb[base]      = (bf16_t)(x0 * cs - x1 * sn);
  kb[base + 32] = (bf16_t)(x1 * cs + x0 * sn);
}

// Flash attention, S^T formulation, KB=128 key tiles, 32 q-rows/wave,
// 2-phase double-buffer + setprio (R11). Parked at ~67us: five structural
// variants (R7-R12) all land 67-90us with every pipe <=48% busy -- chain-
// latency plateau for this decomposition. Kept bit-identical to R5 (best).
__global__ __launch_bounds__(256) void attn_kernel(const bf16_t* __restrict__ q,
                                                   const bf16_t* __restrict__ k,
                                                   const bf16_t* __restrict__ vT,
                                                   bf16_t* __restrict__ out) {
  __shared__ __attribute__((aligned(16))) bf16_t Ks[2][128 * 64];   // [key][d]
  __shared__ __attribute__((aligned(16))) bf16_t Vs[2][64 * 128];   // [d][key]
  const int tid  = threadIdx.x;
  const int wave = tid >> 6, lane = tid & 63;
  const int quad = lane >> 4, lr = lane & 15;
  const int srow = lane >> 3, scol = lane & 7;   // K staging: 8 rows x 8 chunks
  const int vrow = lane >> 4, vcol = lane & 15;  // V staging: 4 rows x 16 chunks
  const int cg = scol ^ srow;                    // K swizzle (row&7 == srow)
  const int qt = blockIdx.x, h = blockIdx.y;
  const int hkv = h >> 2;
  const int qrow0 = qt * 128 + wave * 32;        // 32 q-rows per wave
  const int sw = lr & 7;
  const int c0 = (quad ^ sw) * 8;                // K-frag chunk for d<32
  const int c1 = ((quad + 4) ^ sw) * 8;          // d>=32

  bf16x8 aqA0, aqA1, aqB0, aqB1;
#pragma unroll
  for (int set = 0; set < 2; set++) {
    int row = qrow0 + set * 16 + lr;
    const bf16_t* qp = q + (size_t)row * DMODEL + h * HDIM + quad * 8;
    bf16x8 r0 = *(const bf16x8*)qp;
    bf16x8 r1 = *(const bf16x8*)(qp + 32);
    float srow_f = (float)row;
    bf16x8 a0, a1;
#pragma unroll
    for (int j = 0; j < 8; j++) {
      float freq = __expf(-0.2878231366f * (float)(quad * 8 + j));
      float sn, cs;
      sincosf(srow_f * freq, &sn, &cs);
      float x0 = (float)r0[j], x1 = (float)r1[j];
      a0[j] = (bf16_t)(x0 * cs - x1 * sn);
      a1[j] = (bf16_t)(x1 * cs + x0 * sn);
    }
    if (set == 0) { aqA0 = a0; aqA1 = a1; } else { aqB0 = a0; aqB1 = a1; }
  }

  f32x4 OA[4], OB[4];         // O^T: (d = mt*16+quad*4+r, qrow = lr)
  float lA = 0.f, lB = 0.f;
#pragma unroll
  for (int mt = 0; mt < 4; mt++) { OA[mt] = zero4(); OB[mt] = zero4(); }

#define STAGE_TILE(BUF, KT)                                                              \
  {                                                                                      \
    _Pragma("unroll")                                                                    \
    for (int j = 0; j < 4; j++) {                                                        \
      const bf16_t* gK = k + (size_t)((KT) + wave * 32 + j * 8 + srow) * KVDIM +         \
                         hkv * HDIM + cg * 8;                                            \
      bf16_t* lK = Ks[BUF] + (wave * 32 + j * 8) * 64;                                   \
      __builtin_amdgcn_global_load_lds((const __attribute__((address_space(1))) void*)gK,\
                                       (__attribute__((address_space(3))) void*)lK, 16, 0, 0); \
    }                                                                                    \
    _Pragma("unroll")                                                                    \
    for (int j = 0; j < 4; j++) {                                                        \
      int dg = wave * 16 + j * 4 + vrow;                                                 \
      int cgv = vcol ^ (dg & 7);                                                         \
      const bf16_t* gV = vT + (size_t)(hkv * HDIM + dg) * S_LEN + (KT) + cgv * 8;        \
      bf16_t* lV = Vs[BUF] + (wave * 16 + j * 4) * 128;                                  \
      __builtin_amdgcn_global_load_lds((const __attribute__((address_space(1))) void*)gV,\
                                       (__attribute__((address_space(3))) void*)lV, 16, 0, 0); \
    }                                                                                    \
  }

  STAGE_TILE(0, 0);
  __syncthreads();

  int cur = 0;
  for (int kt = 0; kt < S_LEN; kt += 128) {
    if (kt + 128 < S_LEN) STAGE_TILE(cur ^ 1, kt + 128);
    const bf16_t* Kc = Ks[cur];
    const bf16_t* Vc = Vs[cur];

    s16x4 bpA[8], bpB[8];
#pragma unroll
    for (int nt = 0; nt < 8; nt++) {
      const int rk = (nt * 16 + lr) * 64;
      bf16x8 kb0 = *(const bf16x8*)&Kc[rk + c0];
      bf16x8 kb1 = *(const bf16x8*)&Kc[rk + c1];
      f32x4 sA = zero4(), sB = zero4();
      __builtin_amdgcn_s_setprio(1);
      sA = __builtin_amdgcn_mfma_f32_16x16x32_bf16(kb0, aqA0, sA, 0, 0, 0);
      sA = __builtin_amdgcn_mfma_f32_16x16x32_bf16(kb1, aqA1, sA, 0, 0, 0);
      sB = __builtin_amdgcn_mfma_f32_16x16x32_bf16(kb0, aqB0, sB, 0, 0, 0);
      sB = __builtin_amdgcn_mfma_f32_16x16x32_bf16(kb1, aqB1, sB, 0, 0, 0);
      __builtin_amdgcn_s_setprio(0);
#pragma unroll
      for (int r = 0; r < 4; r++) {
        float pA = __builtin_amdgcn_exp2f(sA[r] * 0.1803368801f);
        lA += pA;
        bpA[nt][r] = __builtin_bit_cast(short, (bf16_t)pA);
        float pB = __builtin_amdgcn_exp2f(sB[r] * 0.1803368801f);
        lB += pB;
        bpB[nt][r] = __builtin_bit_cast(short, (bf16_t)pB);
      }
    }
#pragma unroll
    for (int nt = 0; nt < 8; nt++) {
      const int slot = ((nt * 2 + (quad >> 1)) ^ sw) * 8 + (quad & 1) * 4;
      s16x4 av[4];
#pragma unroll
      for (int mt = 0; mt < 4; mt++)
        av[mt] = *(const s16x4*)&Vc[(mt * 16 + lr) * 128 + slot];
      __builtin_amdgcn_s_setprio(1);
#pragma unroll
      for (int mt = 0; mt < 4; mt++) {
        OA[mt] = __builtin_amdgcn_mfma_f32_16x16x16bf16_1k(av[mt], bpA[nt], OA[mt], 0, 0, 0);
        OB[mt] = __builtin_amdgcn_mfma_f32_16x16x16bf16_1k(av[mt], bpB[nt], OB[mt], 0, 0, 0);
      }
      __builtin_amdgcn_s_setprio(0);
    }
    __syncthreads();
    cur ^= 1;
  }
#undef STAGE_TILE

  lA += __shfl_xor(lA, 16);
  lA += __shfl_xor(lA, 32);
  lB += __shfl_xor(lB, 16);
  lB += __shfl_xor(lB, 32);
  float invA = 1.f / lA;
  float invB = 1.f / lB;

#pragma unroll
  for (int mt = 0; mt < 4; mt++) {
    s16x4 ovA, ovB;
#pragma unroll
    for (int r = 0; r < 4; r++) {
      ovA[r] = __builtin_bit_cast(short, (bf16_t)(OA[mt][r] * invA));
      ovB[r] = __builtin_bit_cast(short, (bf16_t)(OB[mt][r] * invB));
    }
    *(s16x4*)&out[(size_t)(qrow0 + lr) * DMODEL + h * HDIM + mt * 16 + quad * 4] = ovA;
    *(s16x4*)&out[(size_t)(qrow0 + 16 + lr) * DMODEL + h * HDIM + mt * 16 + quad * 4] = ovB;
  }
}

extern "C" void kernel_launch(void* const* d_in, const int* in_sizes, int n_in,
                              void* d_out, int out_size, void* d_ws, size_t ws_size,
                              hipStream_t stream) {
  (void)in_sizes; (void)n_in; (void)out_size; (void)ws_size;
  const float* x  = (const float*)d_in[0];
  const float* Wq = (const float*)d_in[1];
  const float* Wk = (const float*)d_in[2];
  const float* Wv = (const float*)d_in[3];
  const float* Wo = (const float*)d_in[4];

  bf16_t* xb  = (bf16_t*)d_ws;                       // 4M (reused as ab)
  bf16_t* Wqb = xb  + (size_t)4 * 1024 * 1024;       // 4M
  bf16_t* Wkb = Wqb + (size_t)4 * 1024 * 1024;       // 1M
  bf16_t* Wvb = Wkb + (size_t)1024 * 1024;           // 1M
  bf16_t* qb  = Wvb + (size_t)1024 * 1024;           // 4M
  bf16_t* kb  = qb  + (size_t)4 * 1024 * 1024;       // 1M
  bf16_t* vb  = kb  + (size_t)1024 * 1024;           // 1M
  bf16_t* Wob = vb  + (size_t)1024 * 1024;           // 4M (outlives ab=xb)
  bf16_t* ab  = xb;    // x dead after projections

  dim3 blk(256);
  convert_all<<<7168, blk, 0, stream>>>(x, xb, Wq, Wqb, Wk, Wkb, Wv, Wvb, Wo, Wob);
  gemm_proj<<<768, blk, 0, stream>>>(xb, Wqb, Wkb, Wvb, qb, kb, vb);
  rope_k<<<2048, blk, 0, stream>>>(kb);
  attn_kernel<<<dim3(S_LEN / 128, NHEADS), blk, 0, stream>>>(qb, kb, vb, ab);
  gemm_out<<<512, blk, 0, stream>>>(ab, Wob, (float*)d_out);
}

// Round 10
// 234.891 us; speedup vs baseline: 1.2306x; 1.2306x over previous
//
#include <hip/hip_runtime.h>
#include <hip/hip_bf16.h>
#include <cmath>

typedef __bf16 bf16_t;
typedef __attribute__((ext_vector_type(8))) __bf16 bf16x8;
typedef __attribute__((ext_vector_type(4))) float f32x4;
typedef __attribute__((ext_vector_type(4))) short s16x4;

#define S_LEN 2048
#define DMODEL 2048
#define KVDIM 512
#define NHEADS 32
#define NKV 8
#define HDIM 64

__device__ inline f32x4 zero4() { f32x4 z; z[0]=0.f; z[1]=0.f; z[2]=0.f; z[3]=0.f; return z; }

// Inputs are fp32 (established R2-R6: bf16 misread would NaN; we pass at 1.46e-3).
// One dispatch converts all 5 tensors to bf16. 2048 elems/block:
// x 2048 | Wq 2048 | Wk 512 | Wv 512 | Wo 2048 blocks (7168 total).
__global__ void convert_all(const float* __restrict__ s0, bf16_t* __restrict__ d0,
                            const float* __restrict__ s1, bf16_t* __restrict__ d1,
                            const float* __restrict__ s2, bf16_t* __restrict__ d2,
                            const float* __restrict__ s3, bf16_t* __restrict__ d3,
                            const float* __restrict__ s4, bf16_t* __restrict__ d4) {
  int b = blockIdx.x;
  const float* src; bf16_t* dst; int boff;
  if      (b < 2048) { src = s0; dst = d0; boff = b; }
  else if (b < 4096) { src = s1; dst = d1; boff = b - 2048; }
  else if (b < 4608) { src = s2; dst = d2; boff = b - 4096; }
  else if (b < 5120) { src = s3; dst = d3; boff = b - 4608; }
  else               { src = s4; dst = d4; boff = b - 5120; }
  int idx = (boff * 256 + threadIdx.x) * 8;
  bf16x8 v;
#pragma unroll
  for (int j = 0; j < 8; j++) v[j] = (bf16_t)src[idx + j];
  *(bf16x8*)(dst + idx) = v;
}

// GEMM core: C = A(MxK) * Bt(NxK)^T, bf16 in, fp32 accum. Tile 128 x BN, BK=64,
// 4 waves 2x2 -- R5 structure (best measured: 236.56us total). R14/R15's
// counted-vmcnt 3-stage regressed (MfmaUtil 15%->10.7%: 72KB LDS cut residency
// 5->2 blocks/CU per m132, and sched_barrier pinning defeated the compiler per
// m141). Manual waitcnt scheduling is CLOSED for this structure.
// R16: smem passed in from the __global__ (single allocation across template
// instantiations); ROPE flag fuses k-RoPE into the epilogue via LDS exchange
// (the (i,i+32) pair spans the two wn-waves; trailing K-loop barrier makes the
// scratch reuse safe). Deletes the rope_k dispatch.
template <int BN, bool F32OUT, bool ROPE>
__device__ __forceinline__ void gemm_core(const bf16_t* __restrict__ A,
                                          const bf16_t* __restrict__ Bt,
                                          void* __restrict__ Cout,
                                          int N, int K, int bm, int bn,
                                          bf16_t* __restrict__ smem) {
  constexpr int NT_W = BN / 32;    // 16-col acc tiles per wave
  bf16_t* As = smem;               // 128 x 64
  bf16_t* Bs = smem + 128 * 64;    // BN x 64
  const int tid  = threadIdx.x;
  const int wave = tid >> 6, lane = tid & 63;
  const int wm = wave >> 1, wn = wave & 1;
  const int quad = lane >> 4, lr = lane & 15;
  const int srow = lane >> 3, scol = lane & 7;

  f32x4 acc[4][NT_W];
#pragma unroll
  for (int i = 0; i < 4; i++)
#pragma unroll
    for (int j = 0; j < NT_W; j++) acc[i][j] = zero4();

  for (int k0 = 0; k0 < K; k0 += 64) {
#pragma unroll
    for (int i = 0; i < 4; i++) {
      const bf16_t* gA = A + (size_t)(bm + i * 32 + wave * 8 + srow) * K + k0 + scol * 8;
      bf16_t* lA = As + (i * 32 + wave * 8) * 64;
      __builtin_amdgcn_global_load_lds((const __attribute__((address_space(1))) void*)gA,
                                       (__attribute__((address_space(3))) void*)lA, 16, 0, 0);
    }
#pragma unroll
    for (int i = 0; i < BN / 32; i++) {
      const bf16_t* gB = Bt + (size_t)(bn + i * 32 + wave * 8 + srow) * K + k0 + scol * 8;
      bf16_t* lB = Bs + (i * 32 + wave * 8) * 64;
      __builtin_amdgcn_global_load_lds((const __attribute__((address_space(1))) void*)gB,
                                       (__attribute__((address_space(3))) void*)lB, 16, 0, 0);
    }
    __syncthreads();
#pragma unroll
    for (int ks = 0; ks < 2; ks++) {
      bf16x8 a[4], b[NT_W];
#pragma unroll
      for (int mt = 0; mt < 4; mt++)
        a[mt] = *(const bf16x8*)&As[(wm * 64 + mt * 16 + lr) * 64 + ks * 32 + quad * 8];
#pragma unroll
      for (int nt = 0; nt < NT_W; nt++)
        b[nt] = *(const bf16x8*)&Bs[(wn * (BN / 2) + nt * 16 + lr) * 64 + ks * 32 + quad * 8];
#pragma unroll
      for (int mt = 0; mt < 4; mt++)
#pragma unroll
        for (int nt = 0; nt < NT_W; nt++)
          acc[mt][nt] = __builtin_amdgcn_mfma_f32_16x16x32_bf16(a[mt], b[nt], acc[mt][nt], 0, 0, 0);
    }
    __syncthreads();
  }

  if (!ROPE) {
#pragma unroll
    for (int mt = 0; mt < 4; mt++)
#pragma unroll
      for (int nt = 0; nt < NT_W; nt++)
#pragma unroll
        for (int r = 0; r < 4; r++) {
          int row = bm + wm * 64 + mt * 16 + quad * 4 + r;
          int col = bn + wn * (BN / 2) + nt * 16 + lr;
          if (F32OUT) ((float*)Cout)[(size_t)row * N + col] = acc[mt][nt][r];
          else ((bf16_t*)Cout)[(size_t)row * N + col] = (bf16_t)acc[mt][nt][r];
        }
  } else {
    // Fused RoPE (k-projection, BN=64: one 64-col head per block). Pair
    // (i, i+32) lives in waves (wm,0)/(wm,1) at identical mt/nt/quad/lr/r ->
    // exchange through 32KB fp32 scratch overlaying As+Bs (trailing K-loop
    // __syncthreads guarantees all LDS reads done).
    float* sc = (float*)smem;   // [128][64] fp32 = 32KB
#pragma unroll
    for (int mt = 0; mt < 4; mt++)
#pragma unroll
      for (int nt = 0; nt < NT_W; nt++)
#pragma unroll
        for (int r = 0; r < 4; r++) {
          int rl = wm * 64 + mt * 16 + quad * 4 + r;
          int col = wn * (BN / 2) + nt * 16 + lr;
          sc[rl * 64 + col] = acc[mt][nt][r];
        }
    __syncthreads();
#pragma unroll
    for (int mt = 0; mt < 4; mt++)
#pragma unroll
      for (int nt = 0; nt < NT_W; nt++)
#pragma unroll
        for (int r = 0; r < 4; r++) {
          int rl = wm * 64 + mt * 16 + quad * 4 + r;
          int col = wn * (BN / 2) + nt * 16 + lr;
          float x = acc[mt][nt][r];
          float y = sc[rl * 64 + (col ^ 32)];
          int i = col & 31;
          float freq = __expf(-0.2878231366f * (float)i);   // 10000^(-i/32)
          float sn, cs;
          sincosf((float)(bm + rl) * freq, &sn, &cs);
          float o = (col < 32) ? (x * cs - y * sn) : (x * cs + y * sn);
          ((bf16_t*)Cout)[(size_t)(bm + rl) * N + bn + col] = (bf16_t)o;
        }
  }
}

// All three projections, one dispatch, 768 blocks of 128x64 tiles:
// 0..511: q = x Wq^T; 512..639: k = x Wk^T (RoPE fused); 640..767: vT = Wv x^T.
__global__ __launch_bounds__(256) void gemm_proj(const bf16_t* __restrict__ xb,
                                                 const bf16_t* __restrict__ Wqb,
                                                 const bf16_t* __restrict__ Wkb,
                                                 const bf16_t* __restrict__ Wvb,
                                                 bf16_t* __restrict__ qb,
                                                 bf16_t* __restrict__ kb,
                                                 bf16_t* __restrict__ vb) {
  // 32KB: As(16K)+Bs(8K) for the main loop; full 32KB fp32 scratch for RoPE.
  __shared__ __attribute__((aligned(16))) bf16_t smem[128 * 64 + 64 * 64 + 64 * 64];
  int b = blockIdx.x;
  if (b < 512) {
    gemm_core<64, false, false>(xb, Wqb, qb, 2048, 2048, (b >> 5) * 128, (b & 31) * 64, smem);
  } else if (b < 640) {
    int r = b - 512;
    gemm_core<64, false, true>(xb, Wkb, kb, 512, 2048, (r >> 3) * 128, (r & 7) * 64, smem);
  } else {
    int r = b - 640;
    gemm_core<64, false, false>(Wvb, xb, vb, 2048, 2048, (r >> 5) * 128, (r & 31) * 64, smem);
  }
}

// Final projection: out = attn_out Wo^T, fp32 stores. 512 blocks of 128x64.
__global__ __launch_bounds__(256) void gemm_out(const bf16_t* __restrict__ A,
                                                const bf16_t* __restrict__ Bt,
                                                float* __restrict__ C) {
  __shared__ __attribute__((aligned(16))) bf16_t smem[128 * 64 + 64 * 64];
  int b = blockIdx.x;
  gemm_core<64, true, false>(A, Bt, C, 2048, 2048, (b >> 5) * 128, (b & 31) * 64, smem);
}

// Flash attention, S^T formulation, KB=128 key tiles, 32 q-rows/wave,
// 2-phase double-buffer + setprio. Parked at ~67us: five structural variants
// (R7-R12) all land 67-90us with every pipe <=48% busy -- chain-latency
// plateau for this decomposition. Bit-identical to R5 (best: 236.56us).
__global__ __launch_bounds__(256) void attn_kernel(const bf16_t* __restrict__ q,
                                                   const bf16_t* __restrict__ k,
                                                   const bf16_t* __restrict__ vT,
                                                   bf16_t* __restrict__ out) {
  __shared__ __attribute__((aligned(16))) bf16_t Ks[2][128 * 64];   // [key][d]
  __shared__ __attribute__((aligned(16))) bf16_t Vs[2][64 * 128];   // [d][key]
  const int tid  = threadIdx.x;
  const int wave = tid >> 6, lane = tid & 63;
  const int quad = lane >> 4, lr = lane & 15;
  const int srow = lane >> 3, scol = lane & 7;   // K staging: 8 rows x 8 chunks
  const int vrow = lane >> 4, vcol = lane & 15;  // V staging: 4 rows x 16 chunks
  const int cg = scol ^ srow;                    // K swizzle (row&7 == srow)
  const int qt = blockIdx.x, h = blockIdx.y;
  const int hkv = h >> 2;
  const int qrow0 = qt * 128 + wave * 32;        // 32 q-rows per wave
  const int sw = lr & 7;
  const int c0 = (quad ^ sw) * 8;                // K-frag chunk for d<32
  const int c1 = ((quad + 4) ^ sw) * 8;          // d>=32

  bf16x8 aqA0, aqA1, aqB0, aqB1;
#pragma unroll
  for (int set = 0; set < 2; set++) {
    int row = qrow0 + set * 16 + lr;
    const bf16_t* qp = q + (size_t)row * DMODEL + h * HDIM + quad * 8;
    bf16x8 r0 = *(const bf16x8*)qp;
    bf16x8 r1 = *(const bf16x8*)(qp + 32);
    float srow_f = (float)row;
    bf16x8 a0, a1;
#pragma unroll
    for (int j = 0; j < 8; j++) {
      float freq = __expf(-0.2878231366f * (float)(quad * 8 + j));
      float sn, cs;
      sincosf(srow_f * freq, &sn, &cs);
      float x0 = (float)r0[j], x1 = (float)r1[j];
      a0[j] = (bf16_t)(x0 * cs - x1 * sn);
      a1[j] = (bf16_t)(x1 * cs + x0 * sn);
    }
    if (set == 0) { aqA0 = a0; aqA1 = a1; } else { aqB0 = a0; aqB1 = a1; }
  }

  f32x4 OA[4], OB[4];         // O^T: (d = mt*16+quad*4+r, qrow = lr)
  float lA = 0.f, lB = 0.f;
#pragma unroll
  for (int mt = 0; mt < 4; mt++) { OA[mt] = zero4(); OB[mt] = zero4(); }

#define STAGE_TILE(BUF, KT)                                                              \
  {                                                                                      \
    _Pragma("unroll")                                                                    \
    for (int j = 0; j < 4; j++) {                                                        \
      const bf16_t* gK = k + (size_t)((KT) + wave * 32 + j * 8 + srow) * KVDIM +         \
                         hkv * HDIM + cg * 8;                                            \
      bf16_t* lK = Ks[BUF] + (wave * 32 + j * 8) * 64;                                   \
      __builtin_amdgcn_global_load_lds((const __attribute__((address_space(1))) void*)gK,\
                                       (__attribute__((address_space(3))) void*)lK, 16, 0, 0); \
    }                                                                                    \
    _Pragma("unroll")                                                                    \
    for (int j = 0; j < 4; j++) {                                                        \
      int dg = wave * 16 + j * 4 + vrow;                                                 \
      int cgv = vcol ^ (dg & 7);                                                         \
      const bf16_t* gV = vT + (size_t)(hkv * HDIM + dg) * S_LEN + (KT) + cgv * 8;        \
      bf16_t* lV = Vs[BUF] + (wave * 16 + j * 4) * 128;                                  \
      __builtin_amdgcn_global_load_lds((const __attribute__((address_space(1))) void*)gV,\
                                       (__attribute__((address_space(3))) void*)lV, 16, 0, 0); \
    }                                                                                    \
  }

  STAGE_TILE(0, 0);
  __syncthreads();

  int cur = 0;
  for (int kt = 0; kt < S_LEN; kt += 128) {
    if (kt + 128 < S_LEN) STAGE_TILE(cur ^ 1, kt + 128);
    const bf16_t* Kc = Ks[cur];
    const bf16_t* Vc = Vs[cur];

    s16x4 bpA[8], bpB[8];
#pragma unroll
    for (int nt = 0; nt < 8; nt++) {
      const int rk = (nt * 16 + lr) * 64;
      bf16x8 kb0 = *(const bf16x8*)&Kc[rk + c0];
      bf16x8 kb1 = *(const bf16x8*)&Kc[rk + c1];
      f32x4 sA = zero4(), sB = zero4();
      __builtin_amdgcn_s_setprio(1);
      sA = __builtin_amdgcn_mfma_f32_16x16x32_bf16(kb0, aqA0, sA, 0, 0, 0);
      sA = __builtin_amdgcn_mfma_f32_16x16x32_bf16(kb1, aqA1, sA, 0, 0, 0);
      sB = __builtin_amdgcn_mfma_f32_16x16x32_bf16(kb0, aqB0, sB, 0, 0, 0);
      sB = __builtin_amdgcn_mfma_f32_16x16x32_bf16(kb1, aqB1, sB, 0, 0, 0);
      __builtin_amdgcn_s_setprio(0);
#pragma unroll
      for (int r = 0; r < 4; r++) {
        float pA = __builtin_amdgcn_exp2f(sA[r] * 0.1803368801f);
        lA += pA;
        bpA[nt][r] = __builtin_bit_cast(short, (bf16_t)pA);
        float pB = __builtin_amdgcn_exp2f(sB[r] * 0.1803368801f);
        lB += pB;
        bpB[nt][r] = __builtin_bit_cast(short, (bf16_t)pB);
      }
    }
#pragma unroll
    for (int nt = 0; nt < 8; nt++) {
      const int slot = ((nt * 2 + (quad >> 1)) ^ sw) * 8 + (quad & 1) * 4;
      s16x4 av[4];
#pragma unroll
      for (int mt = 0; mt < 4; mt++)
        av[mt] = *(const s16x4*)&Vc[(mt * 16 + lr) * 128 + slot];
      __builtin_amdgcn_s_setprio(1);
#pragma unroll
      for (int mt = 0; mt < 4; mt++) {
        OA[mt] = __builtin_amdgcn_mfma_f32_16x16x16bf16_1k(av[mt], bpA[nt], OA[mt], 0, 0, 0);
        OB[mt] = __builtin_amdgcn_mfma_f32_16x16x16bf16_1k(av[mt], bpB[nt], OB[mt], 0, 0, 0);
      }
      __builtin_amdgcn_s_setprio(0);
    }
    __syncthreads();
    cur ^= 1;
  }
#undef STAGE_TILE

  lA += __shfl_xor(lA, 16);
  lA += __shfl_xor(lA, 32);
  lB += __shfl_xor(lB, 16);
  lB += __shfl_xor(lB, 32);
  float invA = 1.f / lA;
  float invB = 1.f / lB;

#pragma unroll
  for (int mt = 0; mt < 4; mt++) {
    s16x4 ovA, ovB;
#pragma unroll
    for (int r = 0; r < 4; r++) {
      ovA[r] = __builtin_bit_cast(short, (bf16_t)(OA[mt][r] * invA));
      ovB[r] = __builtin_bit_cast(short, (bf16_t)(OB[mt][r] * invB));
    }
    *(s16x4*)&out[(size_t)(qrow0 + lr) * DMODEL + h * HDIM + mt * 16 + quad * 4] = ovA;
    *(s16x4*)&out[(size_t)(qrow0 + 16 + lr) * DMODEL + h * HDIM + mt * 16 + quad * 4] = ovB;
  }
}

extern "C" void kernel_launch(void* const* d_in, const int* in_sizes, int n_in,
                              void* d_out, int out_size, void* d_ws, size_t ws_size,
                              hipStream_t stream) {
  (void)in_sizes; (void)n_in; (void)out_size; (void)ws_size;
  const float* x  = (const float*)d_in[0];
  const float* Wq = (const float*)d_in[1];
  const float* Wk = (const float*)d_in[2];
  const float* Wv = (const float*)d_in[3];
  const float* Wo = (const float*)d_in[4];

  bf16_t* xb  = (bf16_t*)d_ws;                       // 4M (reused as ab)
  bf16_t* Wqb = xb  + (size_t)4 * 1024 * 1024;       // 4M
  bf16_t* Wkb = Wqb + (size_t)4 * 1024 * 1024;       // 1M
  bf16_t* Wvb = Wkb + (size_t)1024 * 1024;           // 1M
  bf16_t* qb  = Wvb + (size_t)1024 * 1024;           // 4M
  bf16_t* kb  = qb  + (size_t)4 * 1024 * 1024;       // 1M
  bf16_t* vb  = kb  + (size_t)1024 * 1024;           // 1M
  bf16_t* Wob = vb  + (size_t)1024 * 1024;           // 4M (outlives ab=xb)
  bf16_t* ab  = xb;    // x dead after projections

  dim3 blk(256);
  convert_all<<<7168, blk, 0, stream>>>(x, xb, Wq, Wqb, Wk, Wkb, Wv, Wvb, Wo, Wob);
  gemm_proj<<<768, blk, 0, stream>>>(xb, Wqb, Wkb, Wvb, qb, kb, vb);
  attn_kernel<<<dim3(S_LEN / 128, NHEADS), blk, 0, stream>>>(qb, kb, vb, ab);
  gemm_out<<<512, blk, 0, stream>>>(ab, Wob, (float*)d_out);
}